// Round 1
// baseline (347.781 us; speedup 1.0000x reference)
//
#include <hip/hip_runtime.h>

// RNNAdder: B=4096, T=128, HID=64, VOCAB=10, EMB=32, OUT=10
// Strategy (round 1, fp32-exact):
//  - Input projection collapsed to 10-entry LUTs P1/P2 (computed per-WG in LDS).
//  - Wave-per-sequence recurrence: lane j owns h[j]; Whh column j in 64 VGPRs;
//    h[i] broadcast via v_readlane -> SGPR operand of v_fmac. 4 acc chains.
//  - tanh via v_exp_f32 + v_rcp_f32.
//  - Output projection every 16 steps from padded LDS h-buffer (stride 68:
//    conflict-free + 16B aligned for ds_read_b128).

#define T_ 128

__device__ __forceinline__ float rl(float x, int lane) {
    return __int_as_float(__builtin_amdgcn_readlane(__float_as_int(x), lane));
}

__global__ __launch_bounds__(256, 4)
void rnn_fused(const int* __restrict__ num1, const int* __restrict__ num2,
               const float* __restrict__ E, const float* __restrict__ Wxh,
               const float* __restrict__ Whh, const float* __restrict__ bias,
               const float* __restrict__ Wd, const float* __restrict__ bd,
               float* __restrict__ out)
{
    __shared__ __align__(16) float P1[10 * 64];     // E[v]@Wxh[:32] + b
    __shared__ __align__(16) float P2[10 * 64];     // E[v]@Wxh[32:]
    __shared__ __align__(16) float WdT[10 * 68];    // WdT[o][k] = Wd[k][o], pad 68
    __shared__ __align__(16) float hbuf[4 * 16 * 68]; // per-wave 16-step h buffer
    __shared__ int   numbuf[4 * 128];               // packed (num1 | num2<<4) per t
    __shared__ float bd_l[16];

    const int tid = threadIdx.x;
    const int w   = tid >> 6;        // wave in WG
    const int j   = tid & 63;        // lane = hidden unit
    const int s   = (blockIdx.x << 2) + w;  // sequence id

    // ---- setup: Wd transpose ----
    for (int idx = tid; idx < 640; idx += 256) {
        int o = idx >> 6, k = idx & 63;
        WdT[o * 68 + k] = Wd[k * 10 + o];
    }
    if (tid < 10) bd_l[tid] = bd[tid];

    // ---- setup: embedding-projection LUTs ----
    for (int idx = tid; idx < 640; idx += 256) {
        int v = idx >> 6, jj = idx & 63;
        float s1 = bias[jj], s2 = 0.f;
        #pragma unroll
        for (int i = 0; i < 32; ++i) {
            float e = E[v * 32 + i];
            s1 = fmaf(e, Wxh[i * 64 + jj], s1);
            s2 = fmaf(e, Wxh[(32 + i) * 64 + jj], s2);
        }
        P1[idx] = s1;
        P2[idx] = s2;
    }

    // ---- setup: stage this wave's token indices ----
    numbuf[(w << 7) + j]      = num1[s * T_ + j]      | (num2[s * T_ + j] << 4);
    numbuf[(w << 7) + j + 64] = num1[s * T_ + j + 64] | (num2[s * T_ + j + 64] << 4);

    // ---- setup: Whh column j into registers (whh[i] = Whh[i][j]) ----
    float whh[64];
    #pragma unroll
    for (int i = 0; i < 64; ++i) whh[i] = Whh[i * 64 + j];

    __syncthreads();

    float h = 0.f;
    float* hb = &hbuf[w * (16 * 68)];
    const int q = j >> 4, tl = j & 15;
    const float4* w0p = (const float4*)(WdT + q * 68);
    const float4* w1p = (const float4*)(WdT + (q + 4) * 68);
    const float4* w2p = (const float4*)(WdT + ((q < 2) ? (q + 8) : 0) * 68);
    const float4* hb4 = (const float4*)(hb + tl * 68);

    for (int tc = 0; tc < 8; ++tc) {
        for (int tt = 0; tt < 16; ++tt) {
            int pk = numbuf[(w << 7) + (tc << 4) + tt];   // broadcast read
            int v1 = pk & 15, v2 = pk >> 4;
            float a0 = P1[(v1 << 6) + j] + P2[(v2 << 6) + j];
            float a1 = 0.f, a2 = 0.f, a3 = 0.f;
            #pragma unroll
            for (int i = 0; i < 16; ++i) {
                a0 = fmaf(rl(h, i),      whh[i],      a0);
                a1 = fmaf(rl(h, i + 16), whh[i + 16], a1);
                a2 = fmaf(rl(h, i + 32), whh[i + 32], a2);
                a3 = fmaf(rl(h, i + 48), whh[i + 48], a3);
            }
            float x = (a0 + a1) + (a2 + a3);
            // tanh(x) = 1 - 2/(exp2(x * 2*log2e) + 1)
            float e2 = __builtin_amdgcn_exp2f(x * 2.885390081777927f);
            h = 1.f - 2.f * __builtin_amdgcn_rcpf(e2 + 1.f);
            hb[tt * 68 + j] = h;
        }
        // ---- output projection for this 16-step chunk ----
        // lane (q, tl): outputs o = q, q+4, and q+8 (q<2) for t = tc*16+tl
        float l0 = 0.f, l1 = 0.f, l2 = 0.f;
        #pragma unroll
        for (int k4 = 0; k4 < 16; ++k4) {
            float4 hv = hb4[k4];
            float4 wa = w0p[k4], wb = w1p[k4], wc = w2p[k4];
            l0 = fmaf(hv.x, wa.x, l0); l0 = fmaf(hv.y, wa.y, l0);
            l0 = fmaf(hv.z, wa.z, l0); l0 = fmaf(hv.w, wa.w, l0);
            l1 = fmaf(hv.x, wb.x, l1); l1 = fmaf(hv.y, wb.y, l1);
            l1 = fmaf(hv.z, wb.z, l1); l1 = fmaf(hv.w, wb.w, l1);
            l2 = fmaf(hv.x, wc.x, l2); l2 = fmaf(hv.y, wc.y, l2);
            l2 = fmaf(hv.z, wc.z, l2); l2 = fmaf(hv.w, wc.w, l2);
        }
        long base = (long)s * 1280 + (long)((tc << 4) + tl) * 10;
        out[base + q]     = l0 + bd_l[q];
        out[base + q + 4] = l1 + bd_l[q + 4];
        if (q < 2) out[base + q + 8] = l2 + bd_l[q + 8];
    }
}

extern "C" void kernel_launch(void* const* d_in, const int* in_sizes, int n_in,
                              void* d_out, int out_size, void* d_ws, size_t ws_size,
                              hipStream_t stream) {
    const int*   num1 = (const int*)d_in[0];
    const int*   num2 = (const int*)d_in[1];
    const float* E    = (const float*)d_in[2];
    const float* Wxh  = (const float*)d_in[3];
    const float* Whh  = (const float*)d_in[4];
    const float* b    = (const float*)d_in[5];
    const float* Wd   = (const float*)d_in[6];
    const float* bd   = (const float*)d_in[7];
    float* out = (float*)d_out;
    rnn_fused<<<1024, 256, 0, stream>>>(num1, num2, E, Wxh, Whh, b, Wd, bd, out);
}

// Round 2
// 142.057 us; speedup vs baseline: 2.4482x; 2.4482x over previous
//
#include <hip/hip_runtime.h>

// RNNAdder on MFMA (round 2): B=4096, T=128, HID=64, VOCAB=10.
// 256 WGs x 256 thr. WG = 16 sequences (one M=16 MFMA tile), 4 waves N-split
// (wave w owns hidden cols w*16..w*16+15). Recurrence via mfma_f32_16x16x32_f16:
//   K-tiles 0,1: h (f16 hi) x Whh ; same tiles again with scaled f16 residual
//   into a 2nd accumulator (C2/2048) => ~fp32-grade h across 128 steps.
//   K-tile 2: one-hot(v1, v2+10) x [P1;P2] f16 tables => xp (bias folded in P1).
// h ring: 8 slots in LDS, row stride 68 dwords (2-way bank alias = free),
// packed (h_hi | h_lo<<16) per dword. 1 barrier/step; +1 per 8-step chunk for
// the output projection (Wd as B-frags, wave w projects tt=2w,2w+1).

typedef _Float16 half8 __attribute__((ext_vector_type(8)));
typedef float floatx4 __attribute__((ext_vector_type(4)));
typedef int intx4 __attribute__((ext_vector_type(4)));

#define MFMA16(A, B, C) __builtin_amdgcn_mfma_f32_16x16x32_f16((A), (B), (C), 0, 0, 0)

__global__ __launch_bounds__(256)
void rnn_mfma(const int* __restrict__ num1, const int* __restrict__ num2,
              const float* __restrict__ E, const float* __restrict__ Wxh,
              const float* __restrict__ Whh, const float* __restrict__ bias,
              const float* __restrict__ Wd, const float* __restrict__ bd,
              float* __restrict__ out)
{
    __shared__ __align__(16) int pool[8 * 1088 + 2048]; // h ring (8 slots) + numpk

    int* hist  = pool;              // slot*1088 + m*68 + hid  (packed h dwords)
    int* numpk = pool + 8 * 1088;   // [t][m]

    const int tid  = threadIdx.x;
    const int w    = tid >> 6;      // wave id = N-block
    const int lane = tid & 63;
    const int c    = lane & 15;     // col-in-tile / seq row for A
    const int q    = lane >> 4;     // quad
    const int g    = blockIdx.x;    // sequence group (16 seqs)

    // ---- startup staging (overlaid on hist region) ----
    float* WhhS = (float*)pool;           // 4096 floats
    float* P1t  = (float*)(pool + 4096);  // 640
    float* P2t  = (float*)(pool + 4736);  // 640
    float* WdS  = (float*)(pool + 5376);  // 640
    for (int i = tid; i < 4096; i += 256) WhhS[i] = Whh[i];
    for (int i = tid; i < 640;  i += 256) WdS[i]  = Wd[i];
    for (int idx = tid; idx < 640; idx += 256) {
        int v = idx >> 6, jj = idx & 63;
        float s1 = bias[jj], s2 = 0.f;
        #pragma unroll
        for (int i = 0; i < 32; ++i) {
            float e = E[v * 32 + i];
            s1 = fmaf(e, Wxh[i * 64 + jj], s1);
            s2 = fmaf(e, Wxh[(32 + i) * 64 + jj], s2);
        }
        P1t[idx] = s1;  // bias folded in
        P2t[idx] = s2;
    }
    __syncthreads();

    // ---- gather B-fragments (B[k][n]: n = lane&15, k = q*8 + j + kt*32) ----
    half8 Wf[2], Pf, Wdf[2];
    #pragma unroll
    for (int kt = 0; kt < 2; ++kt)
        #pragma unroll
        for (int j = 0; j < 8; ++j) {
            int k = kt * 32 + q * 8 + j;
            Wf[kt][j]  = (_Float16)WhhS[k * 64 + w * 16 + c];
            Wdf[kt][j] = (c < 10) ? (_Float16)WdS[k * 10 + c] : (_Float16)0.f;
        }
    #pragma unroll
    for (int j = 0; j < 8; ++j) {
        int i = q * 8 + j;
        float pv = (i < 10) ? P1t[i * 64 + w * 16 + c]
                 : (i < 20) ? P2t[(i - 10) * 64 + w * 16 + c] : 0.f;
        Pf[j] = (_Float16)pv;
    }
    float bdv = (c < 10) ? bd[c] : 0.f;
    __syncthreads();   // everyone done reading staging before hist reuse

    // ---- zero slot 7 (h_{-1} = 0), stage token indices ----
    for (int i = tid; i < 1088; i += 256) hist[7 * 1088 + i] = 0;
    for (int it = 0; it < 8; ++it) {
        int idx = it * 256 + tid;
        int m = idx & 15, t = idx >> 4;
        int s = g * 16 + m;
        numpk[t * 16 + m] = num1[s * 128 + t] | (num2[s * 128 + t] << 4);
    }
    __syncthreads();

    const int abase = c * 68 + q * 8;   // A-read dword offset (+slot +kt*32)
    const int wcol  = w * 16 + c;       // write column
    const floatx4 zero4 = {0.f, 0.f, 0.f, 0.f};

    for (int t = 0; t < 128; ++t) {
        const int sp = ((t + 7) & 7) * 1088;
        const int sc = (t & 7) * 1088;

        // ---- A fragments: h_hi (lo16) and h_lo (hi16) from packed ring ----
        half8 Ah[2], Al[2];
        #pragma unroll
        for (int kt = 0; kt < 2; ++kt) {
            intx4 ra = *(const intx4*)&hist[sp + abase + kt * 32];
            intx4 rb = *(const intx4*)&hist[sp + abase + kt * 32 + 4];
            intx4 lo, hi;
            lo.x = __builtin_amdgcn_perm(ra.y, ra.x, 0x05040100u);
            lo.y = __builtin_amdgcn_perm(ra.w, ra.z, 0x05040100u);
            lo.z = __builtin_amdgcn_perm(rb.y, rb.x, 0x05040100u);
            lo.w = __builtin_amdgcn_perm(rb.w, rb.z, 0x05040100u);
            hi.x = __builtin_amdgcn_perm(ra.y, ra.x, 0x07060302u);
            hi.y = __builtin_amdgcn_perm(ra.w, ra.z, 0x07060302u);
            hi.z = __builtin_amdgcn_perm(rb.y, rb.x, 0x07060302u);
            hi.w = __builtin_amdgcn_perm(rb.w, rb.z, 0x07060302u);
            Ah[kt] = __builtin_bit_cast(half8, lo);
            Al[kt] = __builtin_bit_cast(half8, hi);
        }

        // ---- one-hot A fragment for the xp K-tile ----
        int pk  = numpk[t * 16 + c];
        int v1  = pk & 15;
        int v2p = (pk >> 4) + 10;
        int ib  = q * 8;
        intx4 ohv;
        #define OH(i0) (((((i0) == v1) || ((i0) == v2p)) ? 0x3C00u : 0u))
        ohv.x = OH(ib + 0) | (OH(ib + 1) << 16);
        ohv.y = OH(ib + 2) | (OH(ib + 3) << 16);
        ohv.z = OH(ib + 4) | (OH(ib + 5) << 16);
        ohv.w = OH(ib + 6) | (OH(ib + 7) << 16);
        #undef OH
        half8 Aoh = __builtin_bit_cast(half8, ohv);

        // ---- recurrence MFMAs ----
        floatx4 C1 = MFMA16(Aoh,   Pf,    zero4);
        C1         = MFMA16(Ah[0], Wf[0], C1);
        C1         = MFMA16(Ah[1], Wf[1], C1);
        floatx4 C2 = MFMA16(Al[0], Wf[0], zero4);
        C2         = MFMA16(Al[1], Wf[1], C2);

        // ---- tanh + pack (hi f16 | residual*2048 f16) + ring write ----
        #pragma unroll
        for (int r = 0; r < 4; ++r) {
            float x  = C1[r] + C2[r] * (1.f / 2048.f);
            float e2 = __builtin_amdgcn_exp2f(x * 2.885390081777927f);
            float hv = 1.f - 2.f * __builtin_amdgcn_rcpf(e2 + 1.f);
            _Float16 hh = (_Float16)hv;
            float hif = (float)hh;
            _Float16 hl = (_Float16)((hv - hif) * 2048.f);
            unsigned phi = (unsigned)__builtin_bit_cast(unsigned short, hh);
            unsigned plo = (unsigned)__builtin_bit_cast(unsigned short, hl);
            hist[sc + (q * 4 + r) * 68 + wcol] = (int)(phi | (plo << 16));
        }

        // ---- output projection per 8-step chunk ----
        if ((t & 7) == 7) {
            __syncthreads();   // all columns of all 8 slots visible
            #pragma unroll
            for (int u = 0; u < 2; ++u) {
                int tt = 2 * w + u;
                int sl = tt * 1088;
                half8 Ph[2];
                #pragma unroll
                for (int kt = 0; kt < 2; ++kt) {
                    intx4 ra = *(const intx4*)&hist[sl + abase + kt * 32];
                    intx4 rb = *(const intx4*)&hist[sl + abase + kt * 32 + 4];
                    intx4 lo;
                    lo.x = __builtin_amdgcn_perm(ra.y, ra.x, 0x05040100u);
                    lo.y = __builtin_amdgcn_perm(ra.w, ra.z, 0x05040100u);
                    lo.z = __builtin_amdgcn_perm(rb.y, rb.x, 0x05040100u);
                    lo.w = __builtin_amdgcn_perm(rb.w, rb.z, 0x05040100u);
                    Ph[kt] = __builtin_bit_cast(half8, lo);
                }
                floatx4 Cp = MFMA16(Ph[0], Wdf[0], zero4);
                Cp         = MFMA16(Ph[1], Wdf[1], Cp);
                int tg = (t - 7) + tt;
                if (c < 10) {
                    #pragma unroll
                    for (int r = 0; r < 4; ++r) {
                        int m = q * 4 + r;
                        out[((g * 16 + m) * 128 + tg) * 10 + c] = Cp[r] + bdv;
                    }
                }
            }
        }
        __syncthreads();   // publish this step's h before next step reads
    }
}

extern "C" void kernel_launch(void* const* d_in, const int* in_sizes, int n_in,
                              void* d_out, int out_size, void* d_ws, size_t ws_size,
                              hipStream_t stream) {
    const int*   num1 = (const int*)d_in[0];
    const int*   num2 = (const int*)d_in[1];
    const float* E    = (const float*)d_in[2];
    const float* Wxh  = (const float*)d_in[3];
    const float* Whh  = (const float*)d_in[4];
    const float* b    = (const float*)d_in[5];
    const float* Wd   = (const float*)d_in[6];
    const float* bd   = (const float*)d_in[7];
    float* out = (float*)d_out;
    rnn_mfma<<<256, 256, 0, stream>>>(num1, num2, E, Wxh, Whh, b, Wd, bd, out);
}